// Round 6
// baseline (331.034 us; speedup 1.0000x reference)
//
#include <hip/hip_runtime.h>
#include <hip/hip_bf16.h>

typedef unsigned short u16;
typedef unsigned int u32;

#define N_NODES 50000
#define N_EDGES 800000
#define DHID 256
#define ELLW 64  // ELL row stride; deg is Poisson(16), P(deg>64) ~ 1e-20

typedef __attribute__((ext_vector_type(8))) _Float16 f16x8;
typedef __attribute__((ext_vector_type(4))) float f32x4;
typedef __attribute__((ext_vector_type(2))) float f32x2;

// ---------- helpers ----------
__device__ __forceinline__ u16 f2bf(float f) {
    u32 u = __float_as_uint(f);
    u32 r = (u + 0x7FFFu + ((u >> 16) & 1u)) >> 16;
    return (u16)r;
}
__device__ __forceinline__ u16 f2h(float f) {
    _Float16 h = (_Float16)f;
    union { _Float16 h; u16 u; } c; c.h = h;
    return c.u;
}

// ---------- zero micro-kernel: deg=0 and hs zero row ----------
__global__ void zero_kernel(int* __restrict__ deg, u32* __restrict__ hs32) {
    int j = blockIdx.x * 256 + threadIdx.x;
    if (j < N_NODES) deg[j] = 0;
    if (j < 128) hs32[(size_t)N_NODES * 128 + j] = 0;  // 512 B zero row at hs[N_NODES]
}

// ---------- prep: x->f16 into Af | W->W^T f16 ----------
#define SPLIT_BLKS 12500
#define W_BLKS 512
__global__ void prep_kernel(const float* __restrict__ x, u16* __restrict__ xf,
                            const float* __restrict__ W1, const float* __restrict__ W2,
                            u16* __restrict__ W1t, u16* __restrict__ W2t) {
    const int b = blockIdx.x, tid = threadIdx.x;
    if (b < SPLIT_BLKS) {
        int i = b * 256 + tid;  // n4 = 3.2M exact
        float4 v = ((const float4*)x)[i];
        u16 h0 = f2h(v.x), h1 = f2h(v.y), h2 = f2h(v.z), h3 = f2h(v.w);
        uint2 hv;
        hv.x = (u32)h0 | ((u32)h1 << 16);
        hv.y = (u32)h2 | ((u32)h3 << 16);
        ((uint2*)xf)[i] = hv;
    } else {
        int idx = b - SPLIT_BLKS;  // 0..511
        int y = idx >> 8, n = idx & 255, k = tid;
        const float* W = y ? W2 : W1;
        u16* o = y ? W2t : W1t;
        o[n * 256 + k] = f2h(W[k * 256 + n]);
    }
}

// ---------- ELL fill, 4 independent atomic->store chains per thread ----------
#define FILL_BLKS 782  // ceil(800000/1024)
__global__ void fill_kernel(const int* __restrict__ src, const int* __restrict__ dst,
                            int* __restrict__ deg, u16* __restrict__ col16) {
    const int tid = threadIdx.x;
    const int e0 = blockIdx.x * 1024 + tid;
    int ds[4], ps[4], ss[4];
    bool ok[4];
#pragma unroll
    for (int q = 0; q < 4; ++q) {
        int e = e0 + q * 256;
        ok[q] = (e < N_EDGES);
        if (ok[q]) { ds[q] = dst[e]; ss[q] = src[e]; }
    }
#pragma unroll
    for (int q = 0; q < 4; ++q)
        if (ok[q]) ps[q] = atomicAdd(&deg[ds[q]], 1);
#pragma unroll
    for (int q = 0; q < 4; ++q)
        if (ok[q] && ps[q] < ELLW) col16[(size_t)ds[q] * ELLW + ps[q]] = (u16)ss[q];
}

// ---------- GEMM: zero-LDS, zero-barrier register streaming ----------
// out[row][c] (bf16) = (A @ W)[row][c] * rsqrt(deg[row]+1)
// A f16 [Nn][256] row-major; Bt = W^T f16 [256 n][256 k] (128 KB, L2-resident).
// Per wave: 64 rows x 128 cols, acc 4x8 f32x4. No LDS, no syncthreads.
__global__ __launch_bounds__(256, 2) void gemm_f16_kernel(
    const u16* __restrict__ Af, const u16* __restrict__ Bt,
    const int* __restrict__ deg, u16* __restrict__ out, int M) {
    const int tid = threadIdx.x;
    const int wave = tid >> 6;
    const int lane = tid & 63;
    const int quad = lane >> 4, l16 = lane & 15;
    const int rowbase = blockIdx.x * 256 + wave * 64;
    const int n0 = blockIdx.y * 128;

    f32x4 acc[4][8] = {};

    size_t aoff[4];
#pragma unroll
    for (int rt = 0; rt < 4; ++rt) {
        int ar = rowbase + rt * 16 + l16;
        if (ar >= M) ar = M - 1;  // tail clamp (stores guarded)
        aoff[rt] = (size_t)ar * 256 + quad * 8;
    }
    size_t boff[8];
#pragma unroll
    for (int nt = 0; nt < 8; ++nt)
        boff[nt] = (size_t)(n0 + nt * 16 + l16) * 256 + quad * 8;

    for (int kt = 0; kt < 8; ++kt) {
        const int ko = kt * 32;
        f16x8 bfr[8], afr[4];
#pragma unroll
        for (int nt = 0; nt < 8; ++nt)
            bfr[nt] = *(const f16x8*)&Bt[boff[nt] + ko];
#pragma unroll
        for (int rt = 0; rt < 4; ++rt)
            afr[rt] = *(const f16x8*)&Af[aoff[rt] + ko];
#pragma unroll
        for (int rt = 0; rt < 4; ++rt)
#pragma unroll
            for (int nt = 0; nt < 8; ++nt)
                acc[rt][nt] = __builtin_amdgcn_mfma_f32_16x16x32_f16(afr[rt], bfr[nt], acc[rt][nt], 0, 0, 0);
    }

#pragma unroll
    for (int rt = 0; rt < 4; ++rt) {
#pragma unroll
        for (int r = 0; r < 4; ++r) {
            int row = rowbase + rt * 16 + quad * 4 + r;
            if (row < M) {
                float s = rsqrtf((float)deg[row] + 1.0f);
#pragma unroll
                for (int nt = 0; nt < 8; ++nt) {
                    int c = n0 + nt * 16 + l16;
                    out[(size_t)row * 256 + c] = f2bf(acc[rt][nt][r] * s);
                }
            }
        }
    }
}

// ---------- aggregation (R2 proven): packed accumulate, depth-3 pipelined batches ----------
// one wave per node; lane covers cols 4l..4l+3 (uint2 = 8 B, bf16 rows). Entry 0 = self,
// then neighbors from ELL row (u16 ids), padded to x4 with zero row (hs[Nn]).
// mode 0: write f16 (feeds next GEMM). mode 1: write fp32 to d_out.
__global__ __launch_bounds__(256) void agg_kernel(
    const u16* __restrict__ hs, const u16* __restrict__ col16,
    const int* __restrict__ deg, const float* __restrict__ bias,
    u16* __restrict__ out_f16, float* __restrict__ out_f,
    int mode, int Nn) {
    const int wave = threadIdx.x >> 6, lane = threadIdx.x & 63;
    const int i = blockIdx.x * 4 + wave;
    if (i >= Nn) return;

    const int cnt = deg[i];
    const size_t ebase = (size_t)i * ELLW;
    int entry = Nn;  // zero-row pad
    if (lane == 0) entry = i;
    else if (lane - 1 < cnt) entry = (int)col16[ebase + lane - 1];
    int entries = cnt + 1;
    if (entries > 64) entries = 64;
    const int nb = (entries + 3) >> 2;
    const size_t lofs = (size_t)lane * 4;

    f32x2 a01 = {0.f, 0.f}, a23 = {0.f, 0.f};

#define ISSUE(b, x0, x1, x2, x3)                                                \
    {                                                                           \
        int e0 = __builtin_amdgcn_readlane(entry, (b) * 4 + 0);                 \
        int e1 = __builtin_amdgcn_readlane(entry, (b) * 4 + 1);                 \
        int e2 = __builtin_amdgcn_readlane(entry, (b) * 4 + 2);                 \
        int e3 = __builtin_amdgcn_readlane(entry, (b) * 4 + 3);                 \
        x0 = *(const uint2*)(hs + (size_t)e0 * 256 + lofs);                     \
        x1 = *(const uint2*)(hs + (size_t)e1 * 256 + lofs);                     \
        x2 = *(const uint2*)(hs + (size_t)e2 * 256 + lofs);                     \
        x3 = *(const uint2*)(hs + (size_t)e3 * 256 + lofs);                     \
    }
#define ACCUM(v)                                                                \
    {                                                                           \
        f32x2 p0, p1;                                                           \
        p0.x = __uint_as_float(v.x << 16);                                      \
        p0.y = __uint_as_float(v.x & 0xffff0000u);                              \
        p1.x = __uint_as_float(v.y << 16);                                      \
        p1.y = __uint_as_float(v.y & 0xffff0000u);                              \
        a01 += p0; a23 += p1;                                                   \
    }

    uint2 c0, c1, c2, c3, d0, d1, d2, d3, n0v, n1v, n2v, n3v;
    ISSUE(0, c0, c1, c2, c3);
    if (nb > 1) ISSUE(1, d0, d1, d2, d3);
    for (int b = 0; b < nb; ++b) {
        const bool more2 = (b + 2 < nb);
        if (more2) ISSUE(b + 2, n0v, n1v, n2v, n3v);
        ACCUM(c0); ACCUM(c1); ACCUM(c2); ACCUM(c3);
        c0 = d0; c1 = d1; c2 = d2; c3 = d3;
        d0 = n0v; d1 = n1v; d2 = n2v; d3 = n3v;
    }
    // rare tail: deg > 63 (ELL slot 63; slots beyond ELLW were dropped, P~0)
    {
        int cap = cnt < ELLW ? cnt : ELLW;
        for (int j = 63; j < cap; ++j) {
            int s = (int)col16[ebase + j];
            uint2 v = *(const uint2*)(hs + (size_t)s * 256 + lofs);
            ACCUM(v);
        }
    }
#undef ISSUE
#undef ACCUM

    const float inv = rsqrtf((float)cnt + 1.0f);
    float4 bb = *(const float4*)(bias + lane * 4);
    float r0 = fmaxf(fmaf(a01.x, inv, bb.x), 0.0f);
    float r1 = fmaxf(fmaf(a01.y, inv, bb.y), 0.0f);
    float r2 = fmaxf(fmaf(a23.x, inv, bb.z), 0.0f);
    float r3 = fmaxf(fmaf(a23.y, inv, bb.w), 0.0f);
    const size_t o = (size_t)i * 256 + lane * 4;
    if (mode == 0) {
        u16 h0 = f2h(r0), h1 = f2h(r1), h2 = f2h(r2), h3 = f2h(r3);
        uint2 w;
        w.x = (u32)h0 | ((u32)h1 << 16);
        w.y = (u32)h2 | ((u32)h3 << 16);
        *(uint2*)(out_f16 + o) = w;
    } else {
        *(float4*)(out_f + o) = make_float4(r0, r1, r2, r3);
    }
}

extern "C" void kernel_launch(void* const* d_in, const int* in_sizes, int n_in,
                              void* d_out, int out_size, void* d_ws, size_t ws_size,
                              hipStream_t stream) {
    const float* x = (const float*)d_in[0];
    const int* ei = (const int*)d_in[1];
    const float* W1 = (const float*)d_in[2];
    const float* b1 = (const float*)d_in[3];
    const float* W2 = (const float*)d_in[4];
    const float* b2 = (const float*)d_in[5];
    float* out = (float*)d_out;

    const int Nn = N_NODES, E = N_EDGES;
    const int* srcp = ei;
    const int* dstp = ei + E;

    char* p = (char*)d_ws;
    auto take = [&](size_t bytes) -> void* {
        void* r = (void*)p;
        p += (bytes + 255) & ~(size_t)255;
        return r;
    };
    u16* hs    = (u16*)take((size_t)(Nn + 1) * DHID * 2);  // bf16, +1 zero row
    u16* col16 = (u16*)take((size_t)Nn * ELLW * 2);        // ELL, 6.4 MB
    int* deg   = (int*)take((size_t)Nn * 4);
    u16* W1t   = (u16*)take(256 * 256 * 2);
    u16* W2t   = (u16*)take(256 * 256 * 2);
    // THE EXPERIMENT: f16 A buffer in workspace, NOT in d_out (suspected
    // uncached/fine-grained alloc). Fallback to d_out only if ws is too small.
    size_t used = (size_t)(p - (char*)d_ws);
    size_t af_bytes = (size_t)Nn * DHID * 2;  // 25.6 MB
    u16* Af = (ws_size >= used + af_bytes) ? (u16*)take(af_bytes) : (u16*)d_out;

    zero_kernel<<<196, 256, 0, stream>>>(deg, (u32*)hs);
    prep_kernel<<<SPLIT_BLKS + W_BLKS, 256, 0, stream>>>(x, Af, W1, W2, W1t, W2t);
    fill_kernel<<<FILL_BLKS, 256, 0, stream>>>(srcp, dstp, deg, col16);

    const int gm = (Nn + 255) / 256;  // 196
    // layer 1
    gemm_f16_kernel<<<dim3(gm, 2), 256, 0, stream>>>(Af, W1t, deg, hs, Nn);
    agg_kernel<<<(Nn + 3) / 4, 256, 0, stream>>>(hs, col16, deg, b1, Af, nullptr, 0, Nn);
    // layer 2
    gemm_f16_kernel<<<dim3(gm, 2), 256, 0, stream>>>(Af, W2t, deg, hs, Nn);
    agg_kernel<<<(Nn + 3) / 4, 256, 0, stream>>>(hs, col16, deg, b2, nullptr, out, 1, Nn);
}

// Round 7
// 314.095 us; speedup vs baseline: 1.0539x; 1.0539x over previous
//
#include <hip/hip_runtime.h>
#include <hip/hip_bf16.h>

typedef unsigned short u16;
typedef unsigned int u32;

#define N_NODES 50000
#define N_EDGES 800000
#define DHID 256
#define ELLW 64  // ELL row stride; deg is Poisson(16), P(deg>64) ~ 1e-20

typedef __attribute__((ext_vector_type(8))) _Float16 f16x8;
typedef __attribute__((ext_vector_type(4))) float f32x4;
typedef __attribute__((ext_vector_type(2))) float f32x2;

// ---------- helpers ----------
__device__ __forceinline__ u16 f2bf(float f) {
    u32 u = __float_as_uint(f);
    u32 r = (u + 0x7FFFu + ((u >> 16) & 1u)) >> 16;
    return (u16)r;
}
__device__ __forceinline__ u16 f2h(float f) {
    _Float16 h = (_Float16)f;
    union { _Float16 h; u16 u; } c; c.h = h;
    return c.u;
}
__device__ __forceinline__ void gl_lds16(const void* g, void* l) {
    __builtin_amdgcn_global_load_lds(
        (const __attribute__((address_space(1))) u32*)g,
        (__attribute__((address_space(3))) u32*)l, 16, 0, 0);
}

// ---------- zero + W-transpose: deg=0, hs zero row, W1t/W2t f16 ----------
// blocks 0..195: zeroing; blocks 196..707: W transpose (512 blocks)
__global__ void zero_w_kernel(int* __restrict__ deg, u32* __restrict__ hs32,
                              const float* __restrict__ W1, const float* __restrict__ W2,
                              u16* __restrict__ W1t, u16* __restrict__ W2t) {
    const int b = blockIdx.x, tid = threadIdx.x;
    if (b < 196) {
        int j = b * 256 + tid;
        if (j < N_NODES) deg[j] = 0;
        if (j < 128) hs32[(size_t)N_NODES * 128 + j] = 0;  // 512 B zero row at hs[N_NODES]
    } else {
        int idx = b - 196;  // 0..511
        int y = idx >> 8, n = idx & 255, k = tid;
        const float* W = y ? W2 : W1;
        u16* o = y ? W2t : W1t;
        o[n * 256 + k] = f2h(W[k * 256 + n]);
    }
}

// ---------- ELL fill, 8 independent atomic->store chains per thread ----------
#define FILL_BLKS 391  // ceil(800000/2048)
__global__ void fill_kernel(const int* __restrict__ src, const int* __restrict__ dst,
                            int* __restrict__ deg, u16* __restrict__ col16) {
    const int tid = threadIdx.x;
    const int e0 = blockIdx.x * 2048 + tid;
    int ds[8], ps[8], ss[8];
    bool ok[8];
#pragma unroll
    for (int q = 0; q < 8; ++q) {
        int e = e0 + q * 256;
        ok[q] = (e < N_EDGES);
        if (ok[q]) { ds[q] = dst[e]; ss[q] = src[e]; }
    }
#pragma unroll
    for (int q = 0; q < 8; ++q)
        if (ok[q]) ps[q] = atomicAdd(&deg[ds[q]], 1);
#pragma unroll
    for (int q = 0; q < 8; ++q)
        if (ok[q] && ps[q] < ELLW) col16[(size_t)ds[q] * ELLW + ps[q]] = (u16)ss[q];
}

// ---------- GEMM layer 1: fp32 A (x direct), reg-streaming, cvt in-reg ----------
// out = hs bf16; A = x fp32 [Nn][256]; Bt = W^T f16 [256][256] (L2-resident).
__global__ __launch_bounds__(256, 2) void gemm_f32a_kernel(
    const float* __restrict__ Ax, const u16* __restrict__ Bt,
    const int* __restrict__ deg, u16* __restrict__ out, int M) {
    const int tid = threadIdx.x;
    const int wave = tid >> 6;
    const int lane = tid & 63;
    const int quad = lane >> 4, l16 = lane & 15;
    const int rowbase = blockIdx.x * 256 + wave * 64;
    const int n0 = blockIdx.y * 128;

    f32x4 acc[4][8] = {};

    size_t aoff[4];
#pragma unroll
    for (int rt = 0; rt < 4; ++rt) {
        int ar = rowbase + rt * 16 + l16;
        if (ar >= M) ar = M - 1;  // tail clamp (stores guarded)
        aoff[rt] = (size_t)ar * 256 + quad * 8;
    }
    size_t boff[8];
#pragma unroll
    for (int nt = 0; nt < 8; ++nt)
        boff[nt] = (size_t)(n0 + nt * 16 + l16) * 256 + quad * 8;

    for (int kt = 0; kt < 8; ++kt) {
        const int ko = kt * 32;
        f16x8 bfr[8], afr[4];
#pragma unroll
        for (int nt = 0; nt < 8; ++nt)
            bfr[nt] = *(const f16x8*)&Bt[boff[nt] + ko];
#pragma unroll
        for (int rt = 0; rt < 4; ++rt) {
            float4 u = *(const float4*)&Ax[aoff[rt] + ko];
            float4 v = *(const float4*)&Ax[aoff[rt] + ko + 4];
            f16x8 a;
            a[0] = (_Float16)u.x; a[1] = (_Float16)u.y;
            a[2] = (_Float16)u.z; a[3] = (_Float16)u.w;
            a[4] = (_Float16)v.x; a[5] = (_Float16)v.y;
            a[6] = (_Float16)v.z; a[7] = (_Float16)v.w;
            afr[rt] = a;
        }
#pragma unroll
        for (int rt = 0; rt < 4; ++rt)
#pragma unroll
            for (int nt = 0; nt < 8; ++nt)
                acc[rt][nt] = __builtin_amdgcn_mfma_f32_16x16x32_f16(afr[rt], bfr[nt], acc[rt][nt], 0, 0, 0);
    }

#pragma unroll
    for (int rt = 0; rt < 4; ++rt) {
#pragma unroll
        for (int r = 0; r < 4; ++r) {
            int row = rowbase + rt * 16 + quad * 4 + r;
            if (row < M) {
                float s = rsqrtf((float)deg[row] + 1.0f);
#pragma unroll
                for (int nt = 0; nt < 8; ++nt) {
                    int c = n0 + nt * 16 + l16;
                    out[(size_t)row * 256 + c] = f2bf(acc[rt][nt][r] * s);
                }
            }
        }
    }
}

// ---------- GEMM layer 2: R2-exact LDS gemm (f16 A) ----------
__global__ __launch_bounds__(256) void gemm_f16_kernel(
    const u16* __restrict__ Af, const u16* __restrict__ Bt,
    const int* __restrict__ deg, u16* __restrict__ out, int M) {
    __shared__ u16 As[128 * 32];
    __shared__ u16 Bs[128 * 32];
    const int tid = threadIdx.x;
    const int wave = tid >> 6;
    const int lane = tid & 63;
    const int wm = wave >> 1, wn = wave & 1;
    const int quad = lane >> 4, l16 = lane & 15;
    const int m0 = blockIdx.x * 128;
    const int n0 = blockIdx.y * 128;

    f32x4 acc[4][4] = {};

    const int row0 = tid >> 2, row1 = (256 + tid) >> 2;
    const int kk = (tid & 3) * 8;
    int ar0 = m0 + row0; if (ar0 >= M) ar0 = M - 1;
    int ar1 = m0 + row1; if (ar1 >= M) ar1 = M - 1;
    const size_t aoff0 = (size_t)ar0 * 256 + kk;
    const size_t aoff1 = (size_t)ar1 * 256 + kk;
    const size_t boff0 = (size_t)(n0 + row0) * 256 + kk;
    const size_t boff1 = (size_t)(n0 + row1) * 256 + kk;
    const size_t l0 = (size_t)(wave * 64) * 8;
    const size_t l1 = (size_t)(256 + wave * 64) * 8;

    for (int ko = 0; ko < 8; ++ko) {
        const int koff = ko * 32;
        __syncthreads();
        gl_lds16(Af + aoff0 + koff, &As[l0]);
        gl_lds16(Af + aoff1 + koff, &As[l1]);
        gl_lds16(Bt + boff0 + koff, &Bs[l0]);
        gl_lds16(Bt + boff1 + koff, &Bs[l1]);
        asm volatile("s_waitcnt vmcnt(0)" ::: "memory");
        __syncthreads();

        f16x8 af[4], bf[4];
#pragma unroll
        for (int mi = 0; mi < 4; ++mi)
            af[mi] = *(const f16x8*)&As[(wm * 64 + mi * 16 + l16) * 32 + quad * 8];
#pragma unroll
        for (int ni = 0; ni < 4; ++ni)
            bf[ni] = *(const f16x8*)&Bs[(wn * 64 + ni * 16 + l16) * 32 + quad * 8];
#pragma unroll
        for (int mi = 0; mi < 4; ++mi)
#pragma unroll
            for (int ni = 0; ni < 4; ++ni)
                acc[mi][ni] = __builtin_amdgcn_mfma_f32_16x16x32_f16(af[mi], bf[ni], acc[mi][ni], 0, 0, 0);
    }

#pragma unroll
    for (int mi = 0; mi < 4; ++mi) {
#pragma unroll
        for (int r = 0; r < 4; ++r) {
            int row = m0 + wm * 64 + mi * 16 + quad * 4 + r;
            if (row < M) {
                float s = rsqrtf((float)deg[row] + 1.0f);
#pragma unroll
                for (int ni = 0; ni < 4; ++ni) {
                    int c = n0 + wn * 64 + ni * 16 + l16;
                    out[(size_t)row * 256 + c] = f2bf(acc[mi][ni][r] * s);
                }
            }
        }
    }
}

// ---------- aggregation (R2 proven): packed accumulate, depth-3 pipelined batches ----------
__global__ __launch_bounds__(256) void agg_kernel(
    const u16* __restrict__ hs, const u16* __restrict__ col16,
    const int* __restrict__ deg, const float* __restrict__ bias,
    u16* __restrict__ out_f16, float* __restrict__ out_f,
    int mode, int Nn) {
    const int wave = threadIdx.x >> 6, lane = threadIdx.x & 63;
    const int i = blockIdx.x * 4 + wave;
    if (i >= Nn) return;

    const int cnt = deg[i];
    const size_t ebase = (size_t)i * ELLW;
    int entry = Nn;  // zero-row pad
    if (lane == 0) entry = i;
    else if (lane - 1 < cnt) entry = (int)col16[ebase + lane - 1];
    int entries = cnt + 1;
    if (entries > 64) entries = 64;
    const int nb = (entries + 3) >> 2;
    const size_t lofs = (size_t)lane * 4;

    f32x2 a01 = {0.f, 0.f}, a23 = {0.f, 0.f};

#define ISSUE(b, x0, x1, x2, x3)                                                \
    {                                                                           \
        int e0 = __builtin_amdgcn_readlane(entry, (b) * 4 + 0);                 \
        int e1 = __builtin_amdgcn_readlane(entry, (b) * 4 + 1);                 \
        int e2 = __builtin_amdgcn_readlane(entry, (b) * 4 + 2);                 \
        int e3 = __builtin_amdgcn_readlane(entry, (b) * 4 + 3);                 \
        x0 = *(const uint2*)(hs + (size_t)e0 * 256 + lofs);                     \
        x1 = *(const uint2*)(hs + (size_t)e1 * 256 + lofs);                     \
        x2 = *(const uint2*)(hs + (size_t)e2 * 256 + lofs);                     \
        x3 = *(const uint2*)(hs + (size_t)e3 * 256 + lofs);                     \
    }
#define ACCUM(v)                                                                \
    {                                                                           \
        f32x2 p0, p1;                                                           \
        p0.x = __uint_as_float(v.x << 16);                                      \
        p0.y = __uint_as_float(v.x & 0xffff0000u);                              \
        p1.x = __uint_as_float(v.y << 16);                                      \
        p1.y = __uint_as_float(v.y & 0xffff0000u);                              \
        a01 += p0; a23 += p1;                                                   \
    }

    uint2 c0, c1, c2, c3, d0, d1, d2, d3, n0v, n1v, n2v, n3v;
    ISSUE(0, c0, c1, c2, c3);
    if (nb > 1) ISSUE(1, d0, d1, d2, d3);
    for (int b = 0; b < nb; ++b) {
        const bool more2 = (b + 2 < nb);
        if (more2) ISSUE(b + 2, n0v, n1v, n2v, n3v);
        ACCUM(c0); ACCUM(c1); ACCUM(c2); ACCUM(c3);
        c0 = d0; c1 = d1; c2 = d2; c3 = d3;
        d0 = n0v; d1 = n1v; d2 = n2v; d3 = n3v;
    }
    // rare tail: deg > 63 (ELL slot 63; slots beyond ELLW were dropped, P~0)
    {
        int cap = cnt < ELLW ? cnt : ELLW;
        for (int j = 63; j < cap; ++j) {
            int s = (int)col16[ebase + j];
            uint2 v = *(const uint2*)(hs + (size_t)s * 256 + lofs);
            ACCUM(v);
        }
    }
#undef ISSUE
#undef ACCUM

    const float inv = rsqrtf((float)cnt + 1.0f);
    float4 bb = *(const float4*)(bias + lane * 4);
    float r0 = fmaxf(fmaf(a01.x, inv, bb.x), 0.0f);
    float r1 = fmaxf(fmaf(a01.y, inv, bb.y), 0.0f);
    float r2 = fmaxf(fmaf(a23.x, inv, bb.z), 0.0f);
    float r3 = fmaxf(fmaf(a23.y, inv, bb.w), 0.0f);
    const size_t o = (size_t)i * 256 + lane * 4;
    if (mode == 0) {
        u16 h0 = f2h(r0), h1 = f2h(r1), h2 = f2h(r2), h3 = f2h(r3);
        uint2 w;
        w.x = (u32)h0 | ((u32)h1 << 16);
        w.y = (u32)h2 | ((u32)h3 << 16);
        *(uint2*)(out_f16 + o) = w;
    } else {
        *(float4*)(out_f + o) = make_float4(r0, r1, r2, r3);
    }
}

extern "C" void kernel_launch(void* const* d_in, const int* in_sizes, int n_in,
                              void* d_out, int out_size, void* d_ws, size_t ws_size,
                              hipStream_t stream) {
    const float* x = (const float*)d_in[0];
    const int* ei = (const int*)d_in[1];
    const float* W1 = (const float*)d_in[2];
    const float* b1 = (const float*)d_in[3];
    const float* W2 = (const float*)d_in[4];
    const float* b2 = (const float*)d_in[5];
    float* out = (float*)d_out;

    const int Nn = N_NODES, E = N_EDGES;
    const int* srcp = ei;
    const int* dstp = ei + E;

    char* p = (char*)d_ws;
    auto take = [&](size_t bytes) -> void* {
        void* r = (void*)p;
        p += (bytes + 255) & ~(size_t)255;
        return r;
    };
    u16* hs    = (u16*)take((size_t)(Nn + 1) * DHID * 2);  // bf16, +1 zero row
    u16* col16 = (u16*)take((size_t)Nn * ELLW * 2);        // ELL, 6.4 MB
    int* deg   = (int*)take((size_t)Nn * 4);
    u16* W1t   = (u16*)take(256 * 256 * 2);
    u16* W2t   = (u16*)take(256 * 256 * 2);
    // layer-1 agg output (f16, feeds gemm2). Falls back to d_out scratch if ws small.
    size_t used = (size_t)(p - (char*)d_ws);
    size_t af_bytes = (size_t)Nn * DHID * 2;  // 25.6 MB
    u16* Af = (ws_size >= used + af_bytes) ? (u16*)take(af_bytes) : (u16*)d_out;

    zero_w_kernel<<<708, 256, 0, stream>>>(deg, (u32*)hs, W1, W2, W1t, W2t);
    fill_kernel<<<FILL_BLKS, 256, 0, stream>>>(srcp, dstp, deg, col16);

    // layer 1: gemm reads fp32 x directly (prep deleted)
    gemm_f32a_kernel<<<dim3((Nn + 255) / 256, 2), 256, 0, stream>>>(x, W1t, deg, hs, Nn);
    agg_kernel<<<(Nn + 3) / 4, 256, 0, stream>>>(hs, col16, deg, b1, Af, nullptr, 0, Nn);
    // layer 2: R2-exact LDS gemm on f16 A
    gemm_f16_kernel<<<dim3((Nn + 127) / 128, 2), 256, 0, stream>>>(Af, W2t, deg, hs, Nn);
    agg_kernel<<<(Nn + 3) / 4, 256, 0, stream>>>(hs, col16, deg, b2, nullptr, out, 1, Nn);
}